// Round 4
// baseline (929.197 us; speedup 1.0000x reference)
//
#include <hip/hip_runtime.h>
#include <hip/hip_cooperative_groups.h>
#include <hip/hip_bf16.h>

namespace cg = cooperative_groups;

#define RANK 16
#define EMBED_DIM 128
#define NBLK 1024
#define TPB 256

// ---------------------------------------------------------------------------
// Shared gather+project tile: 64 nodes per call, 256 threads.
// Phase 1: 16 groups x 16 lanes; per node preload <=16 csr ids into lanes
// (one coalesced read), shfl-broadcast, 4 independent U-row loads in flight.
// Phase 2: 8 col-groups x 32 node-slots, 2 nodes/thread (halves V LDS reads).
// ---------------------------------------------------------------------------
__device__ __forceinline__ void gather_project_tile(
        const float* __restrict__ U, const float4* Vs4,
        float (*usum)[RANK + 1],
        const unsigned* __restrict__ counts,
        const unsigned* __restrict__ offsets,
        const unsigned* __restrict__ csr_src,
        float* __restrict__ out, int N, int base, int t) {
    int lane16 = t & 15, g = t >> 4;
    for (int rep = 0; rep < 4; ++rep) {
        int ln = rep * 16 + g;
        int n = base + ln;
        float acc = 0.f;
        if (n < N) {
            unsigned start = offsets[n];
            int deg = (int)counts[n];
            int dd = deg < 16 ? deg : 16;
            unsigned myid = (lane16 < dd) ? csr_src[start + lane16] : 0u;
            int k = 0;
            for (; k + 3 < dd; k += 4) {
                unsigned i0 = __shfl(myid, k + 0, 16);
                unsigned i1 = __shfl(myid, k + 1, 16);
                unsigned i2 = __shfl(myid, k + 2, 16);
                unsigned i3 = __shfl(myid, k + 3, 16);
                float f0 = U[(size_t)i0 * RANK + lane16];
                float f1 = U[(size_t)i1 * RANK + lane16];
                float f2 = U[(size_t)i2 * RANK + lane16];
                float f3 = U[(size_t)i3 * RANK + lane16];
                acc += (f0 + f1) + (f2 + f3);
            }
            for (; k < dd; ++k) {
                unsigned i0 = __shfl(myid, k, 16);
                acc += U[(size_t)i0 * RANK + lane16];
            }
            for (int k2 = 16; k2 < deg; ++k2) {        // rare deg>16 tail
                unsigned s2 = csr_src[start + k2];
                acc += U[(size_t)s2 * RANK + lane16];
            }
        }
        usum[ln][lane16] = acc;
    }
    __syncthreads();

    int ln = t >> 3, c8 = t & 7;
    int n1 = base + ln, n2 = base + ln + 32;
    float a1[RANK], a2[RANK];
#pragma unroll
    for (int k = 0; k < RANK; ++k) { a1[k] = usum[ln][k]; a2[k] = usum[ln + 32][k]; }
    float s1 = 0.f, s2 = 0.f;
    if (n1 < N) s1 = 1.0f / fmaxf((float)counts[n1], 1.0f);
    if (n2 < N) s2 = 1.0f / fmaxf((float)counts[n2], 1.0f);
    float4* out4 = (float4*)out;
#pragma unroll
    for (int s = 0; s < 4; ++s) {
        int c4 = c8 + 8 * s;
        float4 x1 = make_float4(0.f, 0.f, 0.f, 0.f);
        float4 x2 = make_float4(0.f, 0.f, 0.f, 0.f);
#pragma unroll
        for (int k = 0; k < RANK; ++k) {
            float4 v = Vs4[k * 32 + c4];
            x1.x = fmaf(a1[k], v.x, x1.x); x1.y = fmaf(a1[k], v.y, x1.y);
            x1.z = fmaf(a1[k], v.z, x1.z); x1.w = fmaf(a1[k], v.w, x1.w);
            x2.x = fmaf(a2[k], v.x, x2.x); x2.y = fmaf(a2[k], v.y, x2.y);
            x2.z = fmaf(a2[k], v.z, x2.z); x2.w = fmaf(a2[k], v.w, x2.w);
        }
        if (n1 < N) out4[(size_t)n1 * 32 + c4] =
            make_float4(x1.x * s1, x1.y * s1, x1.z * s1, x1.w * s1);
        if (n2 < N) out4[(size_t)n2 * 32 + c4] =
            make_float4(x2.x * s2, x2.y * s2, x2.z * s2, x2.w * s2);
    }
    __syncthreads();   // usum reuse guard for caller's next tile
}

// ---------------------------------------------------------------------------
// Single cooperative kernel: zero+detect | hist | scan(a,b,c) | fill | gather.
// ws layout (u32): flag[1] | counts[N] | offsets[N] | cursors[N] |
//                  partials[1024] | csr_src[E]
// ---------------------------------------------------------------------------
__global__ __launch_bounds__(TPB, 4) void fused_all(
        const float* __restrict__ U, const float* __restrict__ V,
        const unsigned* __restrict__ ei_words, float* __restrict__ out,
        unsigned* __restrict__ ws, int N, int E, int nwords) {
    cg::grid_group grid = cg::this_grid();
    __shared__ float4 Vs4[RANK * EMBED_DIM / 4];       // 8 KB
    __shared__ float usum[64][RANK + 1];               // 4.25 KB
    unsigned* ss = (unsigned*)&usum[0][0];             // scan scratch alias

    int t = threadIdx.x, b = blockIdx.x, nB = gridDim.x;
    int gtid = b * TPB + t, gstride = nB * TPB;

    int* flag = (int*)ws;
    unsigned* counts = ws + 1;
    unsigned* offsets = counts + N;
    unsigned* cursors = offsets + N;
    unsigned* partials = cursors + N;
    unsigned* csr_src = partials + 1024;

    const float4* V4 = (const float4*)V;
    Vs4[t] = V4[t];
    Vs4[t + 256] = V4[t + 256];

    // phase 0: zero counts; block 0 detects index dtype (int64 -> odd words 0)
    for (int i = gtid; i < N; i += gstride) counts[i] = 0u;
    if (b == 0) {
        unsigned v = 0;
        for (int i = t; i < 2048; i += TPB) {
            int w = 2 * i + 1;
            if (w < nwords) v |= ei_words[w];
        }
        ss[t] = v; __syncthreads();
        for (int off = 128; off > 0; off >>= 1) {
            if (t < off) ss[t] |= ss[t + off];
            __syncthreads();
        }
        if (t == 0) *flag = (ss[0] != 0) ? 1 : 0;
    }
    grid.sync();

    int f = *(volatile int*)flag;
    const int* ei32 = (const int*)ei_words;

    // phase 1: degree histogram
    for (int e = gtid; e < E; e += gstride) {
        int dst = f ? ei32[E + e] : ei32[2 * (E + e)];
        atomicAdd(&counts[dst], 1u);
    }
    grid.sync();

    // phase 2a: per-256-chunk exclusive scan
    int NB = (N + 255) / 256;
    for (int c = b; c < NB; c += nB) {
        int i = c * 256 + t;
        unsigned v = (i < N) ? counts[i] : 0u;
        ss[t] = v; __syncthreads();
        for (int off = 1; off < 256; off <<= 1) {
            unsigned x = (t >= off) ? ss[t - off] : 0u;
            __syncthreads();
            ss[t] += x; __syncthreads();
        }
        if (i < N) offsets[i] = ss[t] - v;
        if (t == 255) partials[c] = ss[255];
        __syncthreads();
    }
    grid.sync();

    // phase 2b: block 0 scans chunk sums (NB <= 1024, 4/thread)
    if (b == 0) {
        int j0 = 4 * t;
        unsigned p0 = (j0 + 0 < NB) ? partials[j0 + 0] : 0u;
        unsigned p1 = (j0 + 1 < NB) ? partials[j0 + 1] : 0u;
        unsigned p2 = (j0 + 2 < NB) ? partials[j0 + 2] : 0u;
        unsigned p3 = (j0 + 3 < NB) ? partials[j0 + 3] : 0u;
        unsigned tsum = p0 + p1 + p2 + p3;
        ss[t] = tsum; __syncthreads();
        for (int off = 1; off < 256; off <<= 1) {
            unsigned x = (t >= off) ? ss[t - off] : 0u;
            __syncthreads();
            ss[t] += x; __syncthreads();
        }
        unsigned base = ss[t] - tsum;
        if (j0 + 0 < NB) partials[j0 + 0] = base;
        if (j0 + 1 < NB) partials[j0 + 1] = base + p0;
        if (j0 + 2 < NB) partials[j0 + 2] = base + p0 + p1;
        if (j0 + 3 < NB) partials[j0 + 3] = base + p0 + p1 + p2;
    }
    grid.sync();

    // phase 2c: add chunk bases; init cursors
    for (int i = gtid; i < N; i += gstride) {
        unsigned o = offsets[i] + partials[i >> 8];
        offsets[i] = o;
        cursors[i] = o;
    }
    grid.sync();

    // phase 3: fill CSR
    for (int e = gtid; e < E; e += gstride) {
        int src, dst;
        if (f) { src = ei32[e];     dst = ei32[E + e]; }
        else   { src = ei32[2 * e]; dst = ei32[2 * (E + e)]; }
        unsigned pos = atomicAdd(&cursors[dst], 1u);
        csr_src[pos] = (unsigned)src;
    }
    grid.sync();

    // phase 4: gather + project, 64-node tiles
    for (int base = b * 64; base < N; base += nB * 64)
        gather_project_tile(U, Vs4, usum, counts, offsets, csr_src, out, N,
                            base, t);
}

// ---------------------------------------------------------------------------
// Fallback path (only if cooperative launch is refused): R3-style pipeline.
// ---------------------------------------------------------------------------
__global__ void k_detect(const unsigned* __restrict__ words, int nwords,
                         int* __restrict__ flag) {
    unsigned v = 0;
    for (int i = threadIdx.x; i < 2048; i += 256) {
        int w = 2 * i + 1;
        if (w < nwords) v |= words[w];
    }
    if (__any(v != 0) && (threadIdx.x & 63) == 0) atomicOr(flag, 1);
}

__global__ void k_hist(const int* __restrict__ ei, const int* __restrict__ flag,
                       unsigned* __restrict__ counts, int E) {
    int e = blockIdx.x * 256 + threadIdx.x;
    if (e >= E) return;
    int dst = *flag ? ei[E + e] : ei[2 * (E + e)];
    atomicAdd(&counts[dst], 1u);
}

__global__ void k_scan1(const unsigned* __restrict__ counts,
                        unsigned* __restrict__ offsets,
                        unsigned* __restrict__ partials, int N) {
    __shared__ unsigned s[256];
    int t = threadIdx.x, i = blockIdx.x * 256 + t;
    unsigned v = (i < N) ? counts[i] : 0u;
    s[t] = v; __syncthreads();
    for (int off = 1; off < 256; off <<= 1) {
        unsigned x = (t >= off) ? s[t - off] : 0u;
        __syncthreads();
        s[t] += x; __syncthreads();
    }
    if (i < N) offsets[i] = s[t] - v;
    if (t == 255) partials[blockIdx.x] = s[255];
}

__global__ void k_scan2(unsigned* __restrict__ partials, int P) {
    __shared__ unsigned s[256];
    int t = threadIdx.x, j0 = 4 * t;
    unsigned p0 = (j0 + 0 < P) ? partials[j0 + 0] : 0u;
    unsigned p1 = (j0 + 1 < P) ? partials[j0 + 1] : 0u;
    unsigned p2 = (j0 + 2 < P) ? partials[j0 + 2] : 0u;
    unsigned p3 = (j0 + 3 < P) ? partials[j0 + 3] : 0u;
    unsigned tsum = p0 + p1 + p2 + p3;
    s[t] = tsum; __syncthreads();
    for (int off = 1; off < 256; off <<= 1) {
        unsigned x = (t >= off) ? s[t - off] : 0u;
        __syncthreads();
        s[t] += x; __syncthreads();
    }
    unsigned base = s[t] - tsum;
    if (j0 + 0 < P) partials[j0 + 0] = base;
    if (j0 + 1 < P) partials[j0 + 1] = base + p0;
    if (j0 + 2 < P) partials[j0 + 2] = base + p0 + p1;
    if (j0 + 3 < P) partials[j0 + 3] = base + p0 + p1 + p2;
}

__global__ void k_scan3(unsigned* __restrict__ offsets,
                        unsigned* __restrict__ cursors,
                        const unsigned* __restrict__ partials, int N) {
    int i = blockIdx.x * 256 + threadIdx.x;
    if (i >= N) return;
    unsigned o = offsets[i] + partials[blockIdx.x];
    offsets[i] = o;
    cursors[i] = o;
}

__global__ void k_fill(const int* __restrict__ ei, const int* __restrict__ flag,
                       unsigned* __restrict__ cursors,
                       unsigned* __restrict__ csr_src, int E) {
    int e = blockIdx.x * 256 + threadIdx.x;
    if (e >= E) return;
    int src, dst;
    if (*flag) { src = ei[e];     dst = ei[E + e]; }
    else       { src = ei[2 * e]; dst = ei[2 * (E + e)]; }
    unsigned pos = atomicAdd(&cursors[dst], 1u);
    csr_src[pos] = (unsigned)src;
}

__global__ __launch_bounds__(256) void k_gather2(
        const float* __restrict__ U, const float* __restrict__ V,
        const unsigned* __restrict__ counts,
        const unsigned* __restrict__ offsets,
        const unsigned* __restrict__ csr_src,
        float* __restrict__ out, int N) {
    __shared__ float4 Vs4[RANK * EMBED_DIM / 4];
    __shared__ float usum[64][RANK + 1];
    int t = threadIdx.x;
    const float4* V4 = (const float4*)V;
    Vs4[t] = V4[t]; Vs4[t + 256] = V4[t + 256];
    __syncthreads();
    gather_project_tile(U, Vs4, usum, counts, offsets, csr_src, out, N,
                        blockIdx.x * 64, t);
}

extern "C" void kernel_launch(void* const* d_in, const int* in_sizes, int n_in,
                              void* d_out, int out_size, void* d_ws, size_t ws_size,
                              hipStream_t stream) {
    const float* U = (const float*)d_in[0];
    const float* V = (const float*)d_in[1];
    const unsigned* EI = (const unsigned*)d_in[2];
    float* out = (float*)d_out;

    int N = in_sizes[0] / RANK;            // 200000
    int E = in_sizes[2] / 2;               // 640000
    int nwords = in_sizes[2];

    unsigned* ws = (unsigned*)d_ws;

    void* args[] = { (void*)&U, (void*)&V, (void*)&EI, (void*)&out,
                     (void*)&ws, (void*)&N, (void*)&E, (void*)&nwords };
    hipError_t err = hipLaunchCooperativeKernel((void*)fused_all, dim3(NBLK),
                                                dim3(TPB), args, 0, stream);
    if (err != hipSuccess) {
        (void)hipGetLastError();           // clear; run multi-kernel fallback
        int* flag = (int*)ws;
        unsigned* counts = ws + 1;
        unsigned* offsets = counts + N;
        unsigned* cursors = offsets + N;
        unsigned* partials = cursors + N;
        unsigned* csr_src = partials + 1024;
        const int NB = (N + 255) / 256;
        const int EB = (E + 255) / 256;
        hipMemsetAsync(ws, 0, sizeof(unsigned) * (size_t)(N + 1), stream);
        k_detect<<<1, 256, 0, stream>>>(EI, nwords, flag);
        k_hist<<<EB, 256, 0, stream>>>((const int*)EI, flag, counts, E);
        k_scan1<<<NB, 256, 0, stream>>>(counts, offsets, partials, N);
        k_scan2<<<1, 256, 0, stream>>>(partials, NB);
        k_scan3<<<NB, 256, 0, stream>>>(offsets, cursors, partials, N);
        k_fill<<<EB, 256, 0, stream>>>((const int*)EI, flag, cursors, csr_src, E);
        k_gather2<<<(N + 63) / 64, 256, 0, stream>>>(U, V, counts, offsets,
                                                     csr_src, out, N);
    }
}

// Round 5
// 359.326 us; speedup vs baseline: 2.5859x; 2.5859x over previous
//
#include <hip/hip_runtime.h>
#include <hip/hip_bf16.h>

#define RANK 16
#define EMBED_DIM 128
#define NODES_PER_BIN 64

// ---------------------------------------------------------------------------
// ws layout (u32):
//   bin_counts[NBINS] | bin_offsets[NBINS+1] | bin_cursors[NBINS] | records[E]
// Only bin_counts (12.5 KB) needs zeroing.
// Record = (src << 6) | (dst & 63); src < 200000 < 2^18 -> fits u32.
// ---------------------------------------------------------------------------

// Per-wave inline dtype detect: int64 layout => odd 32-bit words (high halves
// of node ids) are all zero over the first 512 pairs; int32 => random ids.
// Every wave reduces the same 512 words -> block-uniform result, no flag mem.
__device__ __forceinline__ bool detect_i32(const unsigned* __restrict__ w,
                                           int nwords) {
    unsigned v = 0;
#pragma unroll
    for (int r = 0; r < 8; ++r) {
        int idx = 2 * ((int)(threadIdx.x & 63) + 64 * r) + 1;
        if (idx < nwords) v |= w[idx];
    }
    return __any(v != 0);
}

// K1: per-bin edge histogram (640K int atomics onto 3125 L2-resident words).
__global__ void bin_hist(const unsigned* __restrict__ ei,
                         unsigned* __restrict__ bin_counts,
                         int E, int nwords) {
    bool i32 = detect_i32(ei, nwords);
    const int* p = (const int*)ei;
    int e = blockIdx.x * 256 + threadIdx.x;
    if (e >= E) return;
    int dst = i32 ? p[E + e] : p[2 * (E + e)];
    atomicAdd(&bin_counts[dst >> 6], 1u);
}

// K2: exclusive scan of bin_counts (NBINS <= 4096) in one block; writes
// offsets, cursors, and offsets[nbins] = E.
__global__ __launch_bounds__(1024) void bin_scan(
        const unsigned* __restrict__ bin_counts,
        unsigned* __restrict__ bin_offsets,
        unsigned* __restrict__ bin_cursors, int nbins) {
    __shared__ unsigned s[1024];
    int t = threadIdx.x;
    unsigned c[4], tsum = 0;
#pragma unroll
    for (int i = 0; i < 4; ++i) {
        int idx = 4 * t + i;
        c[i] = (idx < nbins) ? bin_counts[idx] : 0u;
        tsum += c[i];
    }
    s[t] = tsum; __syncthreads();
    for (int off = 1; off < 1024; off <<= 1) {
        unsigned x = (t >= off) ? s[t - off] : 0u;
        __syncthreads();
        s[t] += x; __syncthreads();
    }
    unsigned run = s[t] - tsum;   // exclusive base for this thread's 4 bins
#pragma unroll
    for (int i = 0; i < 4; ++i) {
        int idx = 4 * t + i;
        if (idx < nbins) { bin_offsets[idx] = run; bin_cursors[idx] = run; }
        run += c[i];
    }
    if (t == 1023) bin_offsets[nbins] = s[1023];
}

// K3: scatter packed records into bin-CSR slots (640K int atomics).
__global__ void bin_fill(const unsigned* __restrict__ ei,
                         unsigned* __restrict__ bin_cursors,
                         unsigned* __restrict__ records,
                         int E, int nwords) {
    bool i32 = detect_i32(ei, nwords);
    const int* p = (const int*)ei;
    int e = blockIdx.x * 256 + threadIdx.x;
    if (e >= E) return;
    int src, dst;
    if (i32) { src = p[e];     dst = p[E + e]; }
    else     { src = p[2 * e]; dst = p[2 * (E + e)]; }
    unsigned pos = atomicAdd(&bin_cursors[dst >> 6], 1u);
    records[pos] = ((unsigned)src << 6) | (unsigned)(dst & 63);
}

// K4: per-bin accumulate (LDS ds_add_f32) + project + write.
// Block = 256 threads owns 64 nodes. Phase 1: 16 groups x 16 lanes; each
// group processes one edge/iter: broadcast record, coalesced 64B U-row load,
// LDS atomic add into usum[d6][lane]. Phase 2: thread t -> col4 = t&31,
// nodes (t>>5)*8 .. +7; float4 LDS reads of usum, V from global (L1-hot),
// coalesced float4 stores.
__global__ __launch_bounds__(256, 4) void accum_project(
        const float* __restrict__ U, const float* __restrict__ V,
        const unsigned* __restrict__ bin_offsets,
        const unsigned* __restrict__ records,
        float* __restrict__ out, int N) {
    __shared__ float usum[NODES_PER_BIN * RANK];   // 4 KB, unpadded (b128 reads)
    __shared__ unsigned ucnt[NODES_PER_BIN];
    int t = threadIdx.x;
    int bin = blockIdx.x;
    int base = bin * NODES_PER_BIN;

    float4* us4 = (float4*)usum;
    us4[t] = make_float4(0.f, 0.f, 0.f, 0.f);      // 256 float4 = whole usum
    if (t < NODES_PER_BIN) ucnt[t] = 0u;
    __syncthreads();

    unsigned start = bin_offsets[bin];
    unsigned end   = bin_offsets[bin + 1];
    int g = t >> 4, lane = t & 15;
    for (unsigned e = start + g; e < end; e += 16) {
        unsigned rec = records[e];
        unsigned src = rec >> 6;
        unsigned d6  = rec & 63u;
        float val = U[(size_t)src * RANK + lane];
        atomicAdd(&usum[d6 * RANK + lane], val);   // ds_add_f32
        if (lane == 0) atomicAdd(&ucnt[d6], 1u);
    }
    __syncthreads();

    int col4 = t & 31;
    int n0 = (t >> 5) * 8;                         // local node base (0..56)
    const float4* V4 = (const float4*)V;
    float4 acc[8];
#pragma unroll
    for (int i = 0; i < 8; ++i) acc[i] = make_float4(0.f, 0.f, 0.f, 0.f);
#pragma unroll
    for (int k4 = 0; k4 < 4; ++k4) {
        float4 v0 = V4[(4 * k4 + 0) * 32 + col4];
        float4 v1 = V4[(4 * k4 + 1) * 32 + col4];
        float4 v2 = V4[(4 * k4 + 2) * 32 + col4];
        float4 v3 = V4[(4 * k4 + 3) * 32 + col4];
#pragma unroll
        for (int i = 0; i < 8; ++i) {
            float4 a = us4[(n0 + i) * 4 + k4];     // ds_read_b128 (broadcast)
            acc[i].x = fmaf(a.x, v0.x, acc[i].x);
            acc[i].y = fmaf(a.x, v0.y, acc[i].y);
            acc[i].z = fmaf(a.x, v0.z, acc[i].z);
            acc[i].w = fmaf(a.x, v0.w, acc[i].w);
            acc[i].x = fmaf(a.y, v1.x, acc[i].x);
            acc[i].y = fmaf(a.y, v1.y, acc[i].y);
            acc[i].z = fmaf(a.y, v1.z, acc[i].z);
            acc[i].w = fmaf(a.y, v1.w, acc[i].w);
            acc[i].x = fmaf(a.z, v2.x, acc[i].x);
            acc[i].y = fmaf(a.z, v2.y, acc[i].y);
            acc[i].z = fmaf(a.z, v2.z, acc[i].z);
            acc[i].w = fmaf(a.z, v2.w, acc[i].w);
            acc[i].x = fmaf(a.w, v3.x, acc[i].x);
            acc[i].y = fmaf(a.w, v3.y, acc[i].y);
            acc[i].z = fmaf(a.w, v3.z, acc[i].z);
            acc[i].w = fmaf(a.w, v3.w, acc[i].w);
        }
    }

    float4* out4 = (float4*)out;
#pragma unroll
    for (int i = 0; i < 8; ++i) {
        int n = base + n0 + i;
        if (n < N) {
            float s = 1.0f / fmaxf((float)ucnt[n0 + i], 1.0f);
            out4[(size_t)n * (EMBED_DIM / 4) + col4] =
                make_float4(acc[i].x * s, acc[i].y * s,
                            acc[i].z * s, acc[i].w * s);
        }
    }
}

extern "C" void kernel_launch(void* const* d_in, const int* in_sizes, int n_in,
                              void* d_out, int out_size, void* d_ws, size_t ws_size,
                              hipStream_t stream) {
    const float* U = (const float*)d_in[0];
    const float* V = (const float*)d_in[1];
    const unsigned* EI = (const unsigned*)d_in[2];
    float* out = (float*)d_out;

    int N = in_sizes[0] / RANK;            // 200000
    int E = in_sizes[2] / 2;               // 640000
    int nwords = in_sizes[2];
    int nbins = (N + NODES_PER_BIN - 1) / NODES_PER_BIN;   // 3125

    unsigned* ws = (unsigned*)d_ws;
    unsigned* bin_counts  = ws;
    unsigned* bin_offsets = bin_counts + nbins;
    unsigned* bin_cursors = bin_offsets + nbins + 1;
    unsigned* records     = bin_cursors + nbins;

    const int EB = (E + 255) / 256;

    hipMemsetAsync(bin_counts, 0, sizeof(unsigned) * (size_t)nbins, stream);
    bin_hist<<<EB, 256, 0, stream>>>(EI, bin_counts, E, nwords);
    bin_scan<<<1, 1024, 0, stream>>>(bin_counts, bin_offsets, bin_cursors, nbins);
    bin_fill<<<EB, 256, 0, stream>>>(EI, bin_cursors, records, E, nwords);
    accum_project<<<nbins, 256, 0, stream>>>(U, V, bin_offsets, records, out, N);
}